// Round 3
// baseline (391.059 us; speedup 1.0000x reference)
//
#include <hip/hip_runtime.h>

// B=8192, NOBJ=1024; inputs [B,NOBJ,2,3] f32; only row 1 (euler) used.
// loss = sum over pairs of acos(clip(0.5*(trace(Rs*Rt^T)-1))) / B
#define NPAIRS (8192u * 1024u)   // 8,388,608
#define BLOCK  256
#define GRID   2048
#define WAVES_PER_BLOCK 4
#define NWAVES (GRID * WAVES_PER_BLOCK)      // 8192
#define F4_PER_TILE 192                      // 128 pairs * 24B / 16B
#define PAIRS_PER_TILE 128
#define NTILES (NPAIRS / PAIRS_PER_TILE)     // 65536 -> exactly 8 tiles/wave
#define EPSF   1e-6f

// trace(R(e0) R(e1)^T) via angle differences (algebraically reduced):
//   trace = cp0*cp1*(cos(dr)+cos(dy)) + sp0*sp1
//         + (1 + sp0*sp1)*cos(dr)*cos(dy) + (sp0+sp1)*sin(dr)*sin(dy)
__device__ __forceinline__ float pair_loss(float r0, float p0, float y0,
                                           float r1, float p1, float y1) {
    float sp0 = __sinf(p0), cp0 = __cosf(p0);
    float sp1 = __sinf(p1), cp1 = __cosf(p1);
    float dr = r1 - r0, dy = y1 - y0;
    float sdr = __sinf(dr), cdr = __cosf(dr);
    float sdy = __sinf(dy), cdy = __cosf(dy);

    float m2 = sp0 * sp1;
    float cc = cdr * cdy;
    float tr = cp0 * cp1 * (cdr + cdy);
    tr += m2;
    tr += fmaf(m2, cc, cc);                    // (1 + sp0*sp1)*cc
    tr = fmaf(sp0 + sp1, sdr * sdy, tr);

    float theta = fmaf(0.5f, tr, -0.5f);
    theta = fminf(fmaxf(theta, -1.0f + EPSF), 1.0f - EPSF);
    return acosf(theta);
}

// Wave-private tile: 192 float4 (=128 pairs) per tensor.
// Global loads are lane-contiguous (f4 idx = base + s*64 + lane): 1KB/instr.
// LDS stage in read-transposed order: f4 m -> slot (m%3)*64 + m/3, so the
// read-back (slot r*64+lane, r=0..2) is lane-contiguous ds_read_b128,
// conflict-free. Thread `lane` then holds f4s {3*lane, 3*lane+1, 3*lane+2}
// = 12 consecutive floats = 2 complete pairs:
//   pair A euler = o0.w,o1.x,o1.y ; pair B euler = o2.y,o2.z,o2.w
// One tensor staged at a time through the same LDS buffer (DS ops are
// in-order within a wave, so read-before-overwrite is safe; no barriers).
__global__ __launch_bounds__(BLOCK) void rot_loss_partial(
    const float4* __restrict__ outp, const float4* __restrict__ targ,
    float* __restrict__ partial) {
    __shared__ float4 lds[WAVES_PER_BLOCK][F4_PER_TILE];  // 12 KB/block
    const int lane = threadIdx.x & 63;
    const int wave = threadIdx.x >> 6;
    const unsigned gwave = blockIdx.x * WAVES_PER_BLOCK + wave;
    float4* wl = lds[wave];

    // loop-invariant staged-write slots for this lane's three f4s
    const unsigned m0 = lane, m1 = 64 + lane, m2 = 128 + lane;
    const unsigned w0 = (m0 % 3u) * 64u + m0 / 3u;
    const unsigned w1 = (m1 % 3u) * 64u + m1 / 3u;
    const unsigned w2 = (m2 % 3u) * 64u + m2 / 3u;

    float acc = 0.0f;
    #pragma unroll 1
    for (unsigned tile = gwave; tile < NTILES; tile += NWAVES) {
        const unsigned base = tile * F4_PER_TILE;
        float4 a0 = outp[base + m0];
        float4 a1 = outp[base + m1];
        float4 a2 = outp[base + m2];
        float4 b0 = targ[base + m0];
        float4 b1 = targ[base + m1];
        float4 b2 = targ[base + m2];

        wl[w0] = a0; wl[w1] = a1; wl[w2] = a2;
        float4 o0 = wl[lane];
        float4 o1 = wl[64 + lane];
        float4 o2 = wl[128 + lane];

        wl[w0] = b0; wl[w1] = b1; wl[w2] = b2;
        float4 t0 = wl[lane];
        float4 t1 = wl[64 + lane];
        float4 t2 = wl[128 + lane];

        acc += pair_loss(o0.w, o1.x, o1.y, t0.w, t1.x, t1.y);
        acc += pair_loss(o2.y, o2.z, o2.w, t2.y, t2.z, t2.w);
    }

    // wave-64 shuffle reduce
    #pragma unroll
    for (int off = 32; off > 0; off >>= 1) acc += __shfl_down(acc, off);

    __shared__ float ws[BLOCK / 64];
    if (lane == 0) ws[wave] = acc;
    __syncthreads();
    if (threadIdx.x == 0) {
        float s = 0.0f;
        #pragma unroll
        for (int w = 0; w < BLOCK / 64; ++w) s += ws[w];
        partial[blockIdx.x] = s;  // written unconditionally (d_ws is poisoned)
    }
}

__global__ __launch_bounds__(BLOCK) void rot_loss_final(
    const float* __restrict__ partial, float* __restrict__ out) {
    double acc = 0.0;
    for (int i = threadIdx.x; i < GRID; i += BLOCK) acc += (double)partial[i];
    #pragma unroll
    for (int off = 32; off > 0; off >>= 1) acc += __shfl_down(acc, off);
    __shared__ double ws[BLOCK / 64];
    const int lane = threadIdx.x & 63;
    const int wave = threadIdx.x >> 6;
    if (lane == 0) ws[wave] = acc;
    __syncthreads();
    if (threadIdx.x == 0) {
        double s = 0.0;
        #pragma unroll
        for (int w = 0; w < BLOCK / 64; ++w) s += ws[w];
        out[0] = (float)(s / 8192.0);
    }
}

extern "C" void kernel_launch(void* const* d_in, const int* in_sizes, int n_in,
                              void* d_out, int out_size, void* d_ws, size_t ws_size,
                              hipStream_t stream) {
    const float4* outp = (const float4*)d_in[0];
    const float4* targ = (const float4*)d_in[1];
    float* partial = (float*)d_ws;  // GRID floats = 8 KiB
    float* out = (float*)d_out;

    rot_loss_partial<<<GRID, BLOCK, 0, stream>>>(outp, targ, partial);
    rot_loss_final<<<1, BLOCK, 0, stream>>>(partial, out);
}